// Round 1
// baseline (5068.428 us; speedup 1.0000x reference)
//
#include <hip/hip_runtime.h>
#include <hip/hip_bf16.h>

#define N_NODES 50000
#define N_EDGES 800000
#define F_IN    768
#define H_DIM   256
#define N_B     32
#define N_G     4
#define C1      1280
#define C2      640

// ---------------- CSR build ----------------

__global__ void count_deg_kernel(const int* __restrict__ dst, int* __restrict__ deg, int n_edges) {
    int e = blockIdx.x * blockDim.x + threadIdx.x;
    if (e < n_edges) atomicAdd(&deg[dst[e]], 1);
}

__global__ __launch_bounds__(1024) void scan_kernel(const int* __restrict__ deg,
                                                    int* __restrict__ row_start,
                                                    int* __restrict__ cursor,
                                                    float* __restrict__ dinv, int n) {
    __shared__ int sdata[1024];
    __shared__ int carry_s;
    if (threadIdx.x == 0) carry_s = 0;
    __syncthreads();
    for (int base = 0; base < n; base += 1024) {
        int i = base + threadIdx.x;
        int x = (i < n) ? deg[i] : 0;
        sdata[threadIdx.x] = x;
        __syncthreads();
        for (int off = 1; off < 1024; off <<= 1) {
            int v = (threadIdx.x >= off) ? sdata[threadIdx.x - off] : 0;
            __syncthreads();
            sdata[threadIdx.x] += v;
            __syncthreads();
        }
        int incl = sdata[threadIdx.x];
        int excl = incl - x;
        int carry = carry_s;
        if (i < n) {
            int rs = carry + excl;
            row_start[i] = rs;
            cursor[i] = rs;
            // reference degree includes self-loop: deg_ref = indeg + 1 (always > 0)
            dinv[i] = rsqrtf((float)(x + 1));
        }
        __syncthreads();
        if (threadIdx.x == 1023) carry_s = carry + incl;
        __syncthreads();
    }
    if (threadIdx.x == 0) row_start[n] = carry_s;
}

__global__ void fill_csr_kernel(const int* __restrict__ src, const int* __restrict__ dst,
                                int* __restrict__ cursor, int* __restrict__ csr_src, int n_edges) {
    int e = blockIdx.x * blockDim.x + threadIdx.x;
    if (e < n_edges) {
        int d = dst[e];
        int pos = atomicAdd(&cursor[d], 1);
        csr_src[pos] = src[e];
    }
}

// ---------------- GEMM: C[i][c] = dinv[i] * sum_k A[i][k] * W[k][c] ----------------
// A: [n, K] row-major, W: [K, 256] row-major, C: [n, 256]
// 64x64 tile per block, 256 threads, 4x4 per thread, BK=16.

__global__ __launch_bounds__(256) void gemm_scaled_kernel(const float* __restrict__ A,
                                                          const float* __restrict__ W,
                                                          const float* __restrict__ dinv,
                                                          float* __restrict__ C, int n, int K) {
    __shared__ float As[16][64];   // As[k][m]
    __shared__ float Bs[16][64];   // Bs[k][nn]
    int tid = threadIdx.x;
    int row0 = blockIdx.x * 64, col0 = blockIdx.y * 64;
    int tx = tid & 15, ty = tid >> 4;
    float acc[4][4];
#pragma unroll
    for (int r = 0; r < 4; r++)
#pragma unroll
        for (int c = 0; c < 4; c++) acc[r][c] = 0.f;

    int ar = tid >> 2, ak = (tid & 3) << 2;   // A-tile: row ar (0..63), k-offset ak (0,4,8,12)
    int bk = tid >> 4, bc = (tid & 15) << 2;  // B-tile: k bk (0..15), col-offset bc
    int arow = row0 + ar;

    for (int k0 = 0; k0 < K; k0 += 16) {
        float4 av = make_float4(0.f, 0.f, 0.f, 0.f);
        if (arow < n) av = *(const float4*)(A + (size_t)arow * K + (k0 + ak));
        As[ak + 0][ar] = av.x;
        As[ak + 1][ar] = av.y;
        As[ak + 2][ar] = av.z;
        As[ak + 3][ar] = av.w;
        float4 bv = *(const float4*)(W + (size_t)(k0 + bk) * H_DIM + (col0 + bc));
        *(float4*)&Bs[bk][bc] = bv;
        __syncthreads();
#pragma unroll
        for (int kk = 0; kk < 16; kk++) {
            float4 a = *(const float4*)&As[kk][ty << 2];
            float4 b = *(const float4*)&Bs[kk][tx << 2];
            float a4[4] = {a.x, a.y, a.z, a.w};
            float b4[4] = {b.x, b.y, b.z, b.w};
#pragma unroll
            for (int r = 0; r < 4; r++)
#pragma unroll
                for (int c = 0; c < 4; c++) acc[r][c] += a4[r] * b4[c];
        }
        __syncthreads();
    }
#pragma unroll
    for (int r = 0; r < 4; r++) {
        int row = row0 + (ty << 2) + r;
        if (row < n) {
            float s = dinv[row];
            float4 o = make_float4(acc[r][0] * s, acc[r][1] * s, acc[r][2] * s, acc[r][3] * s);
            *(float4*)(C + (size_t)row * H_DIM + col0 + (tx << 2)) = o;
        }
    }
}

// ---------------- Aggregation: out[i] = maybe_relu(dinv[i]*(Ht[i] + sum_j Ht[j]) + b) --------

__global__ __launch_bounds__(64) void aggregate_kernel(const float* __restrict__ Ht,
                                                       const int* __restrict__ row_start,
                                                       const int* __restrict__ csr_src,
                                                       const float* __restrict__ dinv,
                                                       const float* __restrict__ bias,
                                                       float* __restrict__ out, int do_relu) {
    int i = blockIdx.x;
    int f4 = threadIdx.x << 2;
    const float4* Hv = (const float4*)Ht;
    size_t base = ((size_t)i * H_DIM + f4) >> 2;
    float4 acc = Hv[base];  // self loop
    int s = row_start[i], e = row_start[i + 1];
    for (int p = s; p < e; p++) {
        int j = csr_src[p];
        float4 v = Hv[((size_t)j * H_DIM + f4) >> 2];
        acc.x += v.x; acc.y += v.y; acc.z += v.z; acc.w += v.w;
    }
    float di = dinv[i];
    float4 b = *(const float4*)(bias + f4);
    float4 o = make_float4(acc.x * di + b.x, acc.y * di + b.y,
                           acc.z * di + b.z, acc.w * di + b.w);
    if (do_relu) {
        o.x = fmaxf(o.x, 0.f); o.y = fmaxf(o.y, 0.f);
        o.z = fmaxf(o.z, 0.f); o.w = fmaxf(o.w, 0.f);
    }
    *(float4*)(out + (size_t)i * H_DIM + f4) = o;
}

// ---------------- Pooling ----------------

__global__ __launch_bounds__(256) void pool_kernel(const float* __restrict__ h3,
                                                   const int* __restrict__ batch,
                                                   float* __restrict__ concat,
                                                   float* __restrict__ cnt, int g) {
    __shared__ float acc[N_B][H_DIM];  // 32 KiB
    __shared__ float c_loc[N_B];
    int tid = threadIdx.x;
    for (int b = 0; b < N_B; b++) acc[b][tid] = 0.f;
    if (tid < N_B) c_loc[tid] = 0.f;
    __syncthreads();
    int per = (N_NODES + gridDim.x - 1) / gridDim.x;
    int start = blockIdx.x * per;
    int end = min(N_NODES, start + per);
    for (int i = start; i < end; i++) {
        int b = batch[i];
        acc[b][tid] += h3[(size_t)i * H_DIM + tid];
        if (tid == 0) c_loc[b] += 1.f;
    }
    __syncthreads();
    for (int b = 0; b < N_B; b++) atomicAdd(&concat[b * C1 + g * H_DIM + tid], acc[b][tid]);
    if (tid < N_B) atomicAdd(&cnt[g * N_B + tid], c_loc[tid]);
}

__global__ void pool_div_kernel(float* __restrict__ concat, const float* __restrict__ cnt) {
    int idx = blockIdx.x * blockDim.x + threadIdx.x;  // 4*32*256
    int g = idx >> 13;
    int r = idx & 8191;
    int b = r >> 8;
    int f = r & 255;
    float c = fmaxf(cnt[g * N_B + b], 1.f);
    concat[b * C1 + g * H_DIM + f] /= c;
}

// ---------------- MLP head ----------------

__global__ void xc_kernel(const float* __restrict__ x_code, const float* __restrict__ Wc,
                          const float* __restrict__ bc, float* __restrict__ concat) {
    int idx = blockIdx.x * blockDim.x + threadIdx.x;  // 32*256
    int b = idx >> 8, c = idx & 255;
    float acc = bc[c];
    for (int k = 0; k < F_IN; k++) acc += x_code[b * F_IN + k] * Wc[k * H_DIM + c];
    concat[b * C1 + 4 * H_DIM + c] = fmaxf(acc, 0.f);
}

__global__ void mlp1_kernel(const float* __restrict__ concat, const float* __restrict__ Wl1,
                            const float* __restrict__ bl1, float* __restrict__ hmid) {
    int idx = blockIdx.x * blockDim.x + threadIdx.x;  // 32*640
    int b = idx / C2, c = idx % C2;
    float acc = bl1[c];
    for (int k = 0; k < C1; k++) acc += concat[b * C1 + k] * Wl1[k * C2 + c];
    hmid[b * C2 + c] = fmaxf(acc, 0.f);
}

__global__ void mlp2_kernel(const float* __restrict__ hmid, const float* __restrict__ Wl2,
                            const float* __restrict__ bl2, float* __restrict__ out) {
    int idx = threadIdx.x;  // 64 = 32*2
    if (idx < N_B * 2) {
        int b = idx >> 1, c = idx & 1;
        float acc = bl2[c];
        for (int k = 0; k < C2; k++) acc += hmid[b * C2 + k] * Wl2[k * 2 + c];
        out[b * 2 + c] = acc;
    }
}

// ---------------- Launch ----------------

extern "C" void kernel_launch(void* const* d_in, const int* in_sizes, int n_in,
                              void* d_out, int out_size, void* d_ws, size_t ws_size,
                              hipStream_t stream) {
    const float* x_g[N_G];
    const int* ei[N_G];
    const int* batch[N_G];
    for (int g = 0; g < N_G; g++) {
        x_g[g]   = (const float*)d_in[3 * g + 0];
        ei[g]    = (const int*)d_in[3 * g + 1];
        batch[g] = (const int*)d_in[3 * g + 2];
    }
    const float* x_code = (const float*)d_in[12];
    const float* W1 = (const float*)d_in[13];
    const float* b1 = (const float*)d_in[14];
    const float* W2 = (const float*)d_in[15];
    const float* b2 = (const float*)d_in[16];
    const float* W3 = (const float*)d_in[17];
    const float* b3 = (const float*)d_in[18];
    const float* Wc = (const float*)d_in[19];
    const float* bc = (const float*)d_in[20];
    const float* Wl1 = (const float*)d_in[21];
    const float* bl1 = (const float*)d_in[22];
    const float* Wl2 = (const float*)d_in[23];
    const float* bl2 = (const float*)d_in[24];
    float* out = (float*)d_out;

    char* p = (char*)d_ws;
    auto alloc = [&](size_t bytes) -> void* {
        void* q = (void*)p;
        p += (bytes + 255) & ~(size_t)255;
        return q;
    };
    float* bufA      = (float*)alloc((size_t)N_NODES * H_DIM * 4);
    float* bufB      = (float*)alloc((size_t)N_NODES * H_DIM * 4);
    int*   row_start = (int*)alloc((size_t)(N_NODES + 1) * 4);
    int*   cursor    = (int*)alloc((size_t)N_NODES * 4);
    int*   csr_src   = (int*)alloc((size_t)N_EDGES * 4);
    int*   deg       = (int*)alloc((size_t)N_NODES * 4);
    float* dinv      = (float*)alloc((size_t)N_NODES * 4);
    float* concat    = (float*)alloc((size_t)N_B * C1 * 4);
    float* cnt       = (float*)alloc((size_t)N_G * N_B * 4);
    float* hmid      = (float*)alloc((size_t)N_B * C2 * 4);

    hipMemsetAsync(concat, 0, (size_t)N_B * C1 * 4, stream);
    hipMemsetAsync(cnt, 0, (size_t)N_G * N_B * 4, stream);

    dim3 gemm_grid((N_NODES + 63) / 64, H_DIM / 64);

    for (int g = 0; g < N_G; g++) {
        const int* src = ei[g];
        const int* dst = ei[g] + N_EDGES;
        hipMemsetAsync(deg, 0, (size_t)N_NODES * 4, stream);
        count_deg_kernel<<<(N_EDGES + 255) / 256, 256, 0, stream>>>(dst, deg, N_EDGES);
        scan_kernel<<<1, 1024, 0, stream>>>(deg, row_start, cursor, dinv, N_NODES);
        fill_csr_kernel<<<(N_EDGES + 255) / 256, 256, 0, stream>>>(src, dst, cursor, csr_src, N_EDGES);

        // layer 1: K=768
        gemm_scaled_kernel<<<gemm_grid, 256, 0, stream>>>(x_g[g], W1, dinv, bufA, N_NODES, F_IN);
        aggregate_kernel<<<N_NODES, 64, 0, stream>>>(bufA, row_start, csr_src, dinv, b1, bufB, 1);
        // layer 2: K=256
        gemm_scaled_kernel<<<gemm_grid, 256, 0, stream>>>(bufB, W2, dinv, bufA, N_NODES, H_DIM);
        aggregate_kernel<<<N_NODES, 64, 0, stream>>>(bufA, row_start, csr_src, dinv, b2, bufB, 1);
        // layer 3: K=256, no relu
        gemm_scaled_kernel<<<gemm_grid, 256, 0, stream>>>(bufB, W3, dinv, bufA, N_NODES, H_DIM);
        aggregate_kernel<<<N_NODES, 64, 0, stream>>>(bufA, row_start, csr_src, dinv, b3, bufB, 0);

        pool_kernel<<<128, 256, 0, stream>>>(bufB, batch[g], concat, cnt, g);
    }

    pool_div_kernel<<<(N_G * N_B * H_DIM) / 256, 256, 0, stream>>>(concat, cnt);
    xc_kernel<<<(N_B * H_DIM) / 256, 256, 0, stream>>>(x_code, Wc, bc, concat);
    mlp1_kernel<<<(N_B * C2) / 256, 256, 0, stream>>>(concat, Wl1, bl1, hmid);
    mlp2_kernel<<<1, 64, 0, stream>>>(hmid, Wl2, bl2, out);
}

// Round 2
// 2885.873 us; speedup vs baseline: 1.7563x; 1.7563x over previous
//
#include <hip/hip_runtime.h>
#include <hip/hip_bf16.h>

#define N_NODES 50000
#define N_EDGES 800000
#define F_IN    768
#define H_DIM   256
#define N_B     32
#define N_G     4
#define C1      1280
#define C2      640

typedef unsigned short u16;
typedef unsigned int u32;
typedef __bf16 bf16x8 __attribute__((ext_vector_type(8)));
typedef float f32x4 __attribute__((ext_vector_type(4)));

__device__ inline u16 f2b(float f) {
    u32 u = __builtin_bit_cast(u32, f);
    u += 0x7fffu + ((u >> 16) & 1u);   // RNE (finite values)
    return (u16)(u >> 16);
}
__device__ inline float b2f(u16 h) {
    u32 u = ((u32)h) << 16;
    return __builtin_bit_cast(float, u);
}
__device__ inline u32 pack2(float a, float b) {
    return (u32)f2b(a) | ((u32)f2b(b) << 16);
}

// ---------------- CSR build ----------------

__global__ void count_deg_kernel(const int* __restrict__ dst, int* __restrict__ deg, int n_edges) {
    int e = blockIdx.x * blockDim.x + threadIdx.x;
    if (e < n_edges) atomicAdd(&deg[dst[e]], 1);
}

__global__ __launch_bounds__(1024) void scan_kernel(const int* __restrict__ deg,
                                                    int* __restrict__ row_start,
                                                    int* __restrict__ cursor,
                                                    float* __restrict__ dinv, int n) {
    __shared__ int wsum[16];
    __shared__ int carry_s;
    int tid = threadIdx.x;
    int lane = tid & 63, wid = tid >> 6;
    if (tid == 0) carry_s = 0;
    __syncthreads();
    int final_total = 0;
    for (int base = 0; base < n; base += 1024) {
        int i = base + tid;
        int x = (i < n) ? deg[i] : 0;
        int v = x;
#pragma unroll
        for (int off = 1; off < 64; off <<= 1) {
            int t = __shfl_up(v, off, 64);
            if (lane >= off) v += t;
        }
        if (lane == 63) wsum[wid] = v;
        __syncthreads();  // (A)
        if (wid == 0) {
            int s = (lane < 16) ? wsum[lane] : 0;
#pragma unroll
            for (int off = 1; off < 16; off <<= 1) {
                int t = __shfl_up(s, off, 64);
                if (lane >= off) s += t;
            }
            if (lane < 16) wsum[lane] = s;
        }
        __syncthreads();  // (B)
        int carry = carry_s;
        int total = wsum[15];
        int wexcl = (wid == 0) ? 0 : wsum[wid - 1];
        int excl = carry + wexcl + (v - x);
        if (i < n) {
            row_start[i] = excl;
            cursor[i] = excl;
            dinv[i] = rsqrtf((float)(x + 1));  // self-loop included
        }
        final_total = carry + total;
        __syncthreads();  // (C) all reads of carry_s/wsum done
        if (tid == 0) carry_s = final_total;
    }
    if (tid == 0) row_start[n] = final_total;
}

__global__ void fill_csr_kernel(const int* __restrict__ src, const int* __restrict__ dst,
                                int* __restrict__ cursor, int* __restrict__ csr_src, int n_edges) {
    int e = blockIdx.x * blockDim.x + threadIdx.x;
    if (e < n_edges) {
        int d = dst[e];
        int pos = atomicAdd(&cursor[d], 1);
        csr_src[pos] = src[e];
    }
}

// ---------------- weight prep: W[K][256] fp32 -> Wt[256][K] bf16 ----------------

__global__ void prep_w_kernel(const float* __restrict__ W, u16* __restrict__ Wt, int K) {
    int idx = blockIdx.x * blockDim.x + threadIdx.x;
    if (idx >= K * 256) return;
    int k = idx >> 8, n = idx & 255;
    Wt[(size_t)n * K + k] = f2b(W[idx]);
}

// ---------------- MFMA GEMM: C[i][c] = bf16( dinv[i] * sum_k A[i][k]*W[k][c] ) --------
// A: [n,K] (fp32 or bf16, row-major), Wt: [256][K] bf16 (transposed), C: [n,256] bf16.
// 128x128 tile, BK=32, 256 threads (4 waves in 2x2), 4x4 MFMA 16x16x32 tiles per wave.

__global__ __launch_bounds__(256) void gemm_mfma_kernel(const void* __restrict__ Aptr, int a_fp32,
                                                        const u16* __restrict__ Wt,
                                                        const float* __restrict__ dinv,
                                                        u16* __restrict__ Cout, int n, int K) {
    __shared__ u16 As[128 * 32] __attribute__((aligned(16)));
    __shared__ u16 Bs[128 * 32] __attribute__((aligned(16)));
    int tid = threadIdx.x;
    int row0 = blockIdx.x * 128, col0 = blockIdx.y * 128;
    int wid = tid >> 6, lane = tid & 63;
    int wm = wid >> 1, wn = wid & 1;
    int mlane = lane & 15, kg = lane >> 4;

    f32x4 acc[4][4];
#pragma unroll
    for (int a = 0; a < 4; a++)
#pragma unroll
        for (int b = 0; b < 4; b++)
#pragma unroll
            for (int c = 0; c < 4; c++) acc[a][b][c] = 0.f;

    for (int k0 = 0; k0 < K; k0 += 32) {
        // stage A tile [128 rows][32 k] bf16
        if (a_fp32) {
            const float* A = (const float*)Aptr;
#pragma unroll
            for (int it = 0; it < 2; it++) {
                int c = tid + it * 256;
                int r = c >> 2;
                int koff = (c & 3) << 3;
                int rg = row0 + r; if (rg >= n) rg = n - 1;
                const float* srcp = A + (size_t)rg * K + k0 + koff;
                float4 f0 = *(const float4*)srcp;
                float4 f1 = *(const float4*)(srcp + 4);
                int4 v;
                v.x = (int)pack2(f0.x, f0.y);
                v.y = (int)pack2(f0.z, f0.w);
                v.z = (int)pack2(f1.x, f1.y);
                v.w = (int)pack2(f1.z, f1.w);
                *(int4*)&As[r * 32 + koff] = v;
            }
        } else {
            const u16* A = (const u16*)Aptr;
#pragma unroll
            for (int it = 0; it < 2; it++) {
                int c = tid + it * 256;
                int r = c >> 2;
                int koff = (c & 3) << 3;
                int rg = row0 + r; if (rg >= n) rg = n - 1;
                *(int4*)&As[r * 32 + koff] = *(const int4*)(A + (size_t)rg * K + k0 + koff);
            }
        }
        // stage B tile: Bs[n][k] from Wt
#pragma unroll
        for (int it = 0; it < 2; it++) {
            int c = tid + it * 256;
            int r = c >> 2;
            int koff = (c & 3) << 3;
            *(int4*)&Bs[r * 32 + koff] = *(const int4*)(Wt + (size_t)(col0 + r) * K + k0 + koff);
        }
        __syncthreads();
        bf16x8 af[4], bfv[4];
#pragma unroll
        for (int mi = 0; mi < 4; mi++)
            af[mi] = *(const bf16x8*)&As[(wm * 64 + mi * 16 + mlane) * 32 + kg * 8];
#pragma unroll
        for (int ni = 0; ni < 4; ni++)
            bfv[ni] = *(const bf16x8*)&Bs[(wn * 64 + ni * 16 + mlane) * 32 + kg * 8];
#pragma unroll
        for (int mi = 0; mi < 4; mi++)
#pragma unroll
            for (int ni = 0; ni < 4; ni++)
                acc[mi][ni] = __builtin_amdgcn_mfma_f32_16x16x32_bf16(af[mi], bfv[ni], acc[mi][ni], 0, 0, 0);
        __syncthreads();
    }
    // epilogue: C/D layout col=lane&15, row=(lane>>4)*4+reg
#pragma unroll
    for (int mi = 0; mi < 4; mi++) {
        int rbase = row0 + wm * 64 + mi * 16 + kg * 4;
#pragma unroll
        for (int r = 0; r < 4; r++) {
            int row = rbase + r;
            if (row < n) {
                float s = dinv[row];
#pragma unroll
                for (int ni = 0; ni < 4; ni++) {
                    int col = col0 + wn * 64 + ni * 16 + mlane;
                    Cout[(size_t)row * H_DIM + col] = f2b(acc[mi][ni][r] * s);
                }
            }
        }
    }
}

// ---------------- Aggregation: out[i] = maybe_relu(dinv[i]*(Ht[i] + sum_j Ht[j]) + b) --------

__global__ __launch_bounds__(64) void aggregate_kernel(const u16* __restrict__ Ht,
                                                       const int* __restrict__ row_start,
                                                       const int* __restrict__ csr_src,
                                                       const float* __restrict__ dinv,
                                                       const float* __restrict__ bias,
                                                       u16* __restrict__ out, int do_relu) {
    int i = blockIdx.x;
    int c4 = threadIdx.x << 2;
    ushort4 sv = *(const ushort4*)(Ht + (size_t)i * H_DIM + c4);
    float a0 = b2f(sv.x), a1 = b2f(sv.y), a2 = b2f(sv.z), a3 = b2f(sv.w);
    int s = row_start[i], e = row_start[i + 1];
    for (int p = s; p < e; p++) {
        int j = csr_src[p];
        ushort4 v = *(const ushort4*)(Ht + (size_t)j * H_DIM + c4);
        a0 += b2f(v.x); a1 += b2f(v.y); a2 += b2f(v.z); a3 += b2f(v.w);
    }
    float di = dinv[i];
    float4 b = *(const float4*)(bias + c4);
    float o0 = a0 * di + b.x, o1 = a1 * di + b.y, o2 = a2 * di + b.z, o3 = a3 * di + b.w;
    if (do_relu) {
        o0 = fmaxf(o0, 0.f); o1 = fmaxf(o1, 0.f);
        o2 = fmaxf(o2, 0.f); o3 = fmaxf(o3, 0.f);
    }
    ushort4 ov = make_ushort4(f2b(o0), f2b(o1), f2b(o2), f2b(o3));
    *(ushort4*)(out + (size_t)i * H_DIM + c4) = ov;
}

// ---------------- Pooling ----------------

__global__ __launch_bounds__(256) void pool_kernel(const u16* __restrict__ h3,
                                                   const int* __restrict__ batch,
                                                   float* __restrict__ concat,
                                                   float* __restrict__ cnt, int g) {
    __shared__ float acc[N_B][H_DIM];  // 32 KiB
    __shared__ float c_loc[N_B];
    int tid = threadIdx.x;
    for (int b = 0; b < N_B; b++) acc[b][tid] = 0.f;
    if (tid < N_B) c_loc[tid] = 0.f;
    __syncthreads();
    int per = (N_NODES + gridDim.x - 1) / gridDim.x;
    int start = blockIdx.x * per;
    int end = min(N_NODES, start + per);
    for (int i = start; i < end; i++) {
        int b = batch[i];
        acc[b][tid] += b2f(h3[(size_t)i * H_DIM + tid]);
        if (tid == 0) c_loc[b] += 1.f;
    }
    __syncthreads();
    for (int b = 0; b < N_B; b++) atomicAdd(&concat[b * C1 + g * H_DIM + tid], acc[b][tid]);
    if (tid < N_B) atomicAdd(&cnt[g * N_B + tid], c_loc[tid]);
}

__global__ void pool_div_kernel(float* __restrict__ concat, const float* __restrict__ cnt) {
    int idx = blockIdx.x * blockDim.x + threadIdx.x;  // 4*32*256
    int g = idx >> 13;
    int r = idx & 8191;
    int b = r >> 8;
    int f = r & 255;
    float c = fmaxf(cnt[g * N_B + b], 1.f);
    concat[b * C1 + g * H_DIM + f] /= c;
}

// ---------------- MLP head (fp32, tiny) ----------------

__global__ void xc_kernel(const float* __restrict__ x_code, const float* __restrict__ Wc,
                          const float* __restrict__ bc, float* __restrict__ concat) {
    int idx = blockIdx.x * blockDim.x + threadIdx.x;  // 32*256
    int b = idx >> 8, c = idx & 255;
    float acc = bc[c];
    for (int k = 0; k < F_IN; k++) acc += x_code[b * F_IN + k] * Wc[k * H_DIM + c];
    concat[b * C1 + 4 * H_DIM + c] = fmaxf(acc, 0.f);
}

__global__ void mlp1_kernel(const float* __restrict__ concat, const float* __restrict__ Wl1,
                            const float* __restrict__ bl1, float* __restrict__ hmid) {
    int idx = blockIdx.x * blockDim.x + threadIdx.x;  // 32*640
    int b = idx / C2, c = idx % C2;
    float acc = bl1[c];
    for (int k = 0; k < C1; k++) acc += concat[b * C1 + k] * Wl1[k * C2 + c];
    hmid[b * C2 + c] = fmaxf(acc, 0.f);
}

__global__ void mlp2_kernel(const float* __restrict__ hmid, const float* __restrict__ Wl2,
                            const float* __restrict__ bl2, float* __restrict__ out) {
    int idx = threadIdx.x;  // 64 = 32*2
    if (idx < N_B * 2) {
        int b = idx >> 1, c = idx & 1;
        float acc = bl2[c];
        for (int k = 0; k < C2; k++) acc += hmid[b * C2 + k] * Wl2[k * 2 + c];
        out[b * 2 + c] = acc;
    }
}

// ---------------- Launch ----------------

extern "C" void kernel_launch(void* const* d_in, const int* in_sizes, int n_in,
                              void* d_out, int out_size, void* d_ws, size_t ws_size,
                              hipStream_t stream) {
    const float* x_g[N_G];
    const int* ei[N_G];
    const int* batch[N_G];
    for (int g = 0; g < N_G; g++) {
        x_g[g]   = (const float*)d_in[3 * g + 0];
        ei[g]    = (const int*)d_in[3 * g + 1];
        batch[g] = (const int*)d_in[3 * g + 2];
    }
    const float* x_code = (const float*)d_in[12];
    const float* W1 = (const float*)d_in[13];
    const float* b1 = (const float*)d_in[14];
    const float* W2 = (const float*)d_in[15];
    const float* b2 = (const float*)d_in[16];
    const float* W3 = (const float*)d_in[17];
    const float* b3 = (const float*)d_in[18];
    const float* Wc = (const float*)d_in[19];
    const float* bc = (const float*)d_in[20];
    const float* Wl1 = (const float*)d_in[21];
    const float* bl1 = (const float*)d_in[22];
    const float* Wl2 = (const float*)d_in[23];
    const float* bl2 = (const float*)d_in[24];
    float* out = (float*)d_out;

    char* p = (char*)d_ws;
    auto alloc = [&](size_t bytes) -> void* {
        void* q = (void*)p;
        p += (bytes + 255) & ~(size_t)255;
        return q;
    };
    u16*   bufA      = (u16*)alloc((size_t)N_NODES * H_DIM * 2);
    u16*   bufB      = (u16*)alloc((size_t)N_NODES * H_DIM * 2);
    u16*   Wt1       = (u16*)alloc((size_t)H_DIM * F_IN * 2);
    u16*   Wt2       = (u16*)alloc((size_t)H_DIM * H_DIM * 2);
    u16*   Wt3       = (u16*)alloc((size_t)H_DIM * H_DIM * 2);
    int*   row_start = (int*)alloc((size_t)(N_NODES + 1) * 4);
    int*   cursor    = (int*)alloc((size_t)N_NODES * 4);
    int*   csr_src   = (int*)alloc((size_t)N_EDGES * 4);
    int*   deg       = (int*)alloc((size_t)N_NODES * 4);
    float* dinv      = (float*)alloc((size_t)N_NODES * 4);
    float* concat    = (float*)alloc((size_t)N_B * C1 * 4);
    float* cnt       = (float*)alloc((size_t)N_G * N_B * 4);
    float* hmid      = (float*)alloc((size_t)N_B * C2 * 4);

    hipMemsetAsync(concat, 0, (size_t)N_B * C1 * 4, stream);
    hipMemsetAsync(cnt, 0, (size_t)N_G * N_B * 4, stream);

    // weight prep (bf16 transposed)
    prep_w_kernel<<<(F_IN * 256 + 255) / 256, 256, 0, stream>>>(W1, Wt1, F_IN);
    prep_w_kernel<<<(H_DIM * 256 + 255) / 256, 256, 0, stream>>>(W2, Wt2, H_DIM);
    prep_w_kernel<<<(H_DIM * 256 + 255) / 256, 256, 0, stream>>>(W3, Wt3, H_DIM);

    dim3 gemm_grid((N_NODES + 127) / 128, 2);

    for (int g = 0; g < N_G; g++) {
        const int* src = ei[g];
        const int* dst = ei[g] + N_EDGES;
        hipMemsetAsync(deg, 0, (size_t)N_NODES * 4, stream);
        count_deg_kernel<<<(N_EDGES + 255) / 256, 256, 0, stream>>>(dst, deg, N_EDGES);
        scan_kernel<<<1, 1024, 0, stream>>>(deg, row_start, cursor, dinv, N_NODES);
        fill_csr_kernel<<<(N_EDGES + 255) / 256, 256, 0, stream>>>(src, dst, cursor, csr_src, N_EDGES);

        // layer 1: A = x (fp32), K=768
        gemm_mfma_kernel<<<gemm_grid, 256, 0, stream>>>(x_g[g], 1, Wt1, dinv, bufA, N_NODES, F_IN);
        aggregate_kernel<<<N_NODES, 64, 0, stream>>>(bufA, row_start, csr_src, dinv, b1, bufB, 1);
        // layer 2: A = bufB (bf16), K=256
        gemm_mfma_kernel<<<gemm_grid, 256, 0, stream>>>(bufB, 0, Wt2, dinv, bufA, N_NODES, H_DIM);
        aggregate_kernel<<<N_NODES, 64, 0, stream>>>(bufA, row_start, csr_src, dinv, b2, bufB, 1);
        // layer 3: K=256, no relu
        gemm_mfma_kernel<<<gemm_grid, 256, 0, stream>>>(bufB, 0, Wt3, dinv, bufA, N_NODES, H_DIM);
        aggregate_kernel<<<N_NODES, 64, 0, stream>>>(bufA, row_start, csr_src, dinv, b3, bufB, 0);

        pool_kernel<<<128, 256, 0, stream>>>(bufB, batch[g], concat, cnt, g);
    }

    pool_div_kernel<<<(N_G * N_B * H_DIM) / 256, 256, 0, stream>>>(concat, cnt);
    xc_kernel<<<(N_B * H_DIM) / 256, 256, 0, stream>>>(x_code, Wc, bc, concat);
    mlp1_kernel<<<(N_B * C2) / 256, 256, 0, stream>>>(concat, Wl1, bl1, hmid);
    mlp2_kernel<<<1, 64, 0, stream>>>(hmid, Wl2, bl2, out);
}